// Round 3
// baseline (525.431 us; speedup 1.0000x reference)
//
#include <hip/hip_runtime.h>
#include <float.h>
#include <math.h>

#define K_CODES 1024
#define ED 64
#define NTOK 131072

// ---------------------------------------------------------------------------
// numpy pairwise_sum (n=64 case): 8 accumulators strided 8, plain adds of the
// rounded products, combine ((r0+r1)+(r2+r3))+((r4+r5)+(r6+r7)).
// Must NOT be contracted into fma -> pragma contract(off) in callers.
// NUMERICS ARE FROZEN: round-2 passed with absmax 3.8e-6 (0 argmin flips).
// dot = single sequential fmaf chain over d (BLAS sgemm microkernel order);
// d2 = fmaf(-2,dot,zsq) + e_sq. Do not reassociate.
// ---------------------------------------------------------------------------

// init: e_sq[k] = pairwise sum cb[k][d]^2 ; zero counts + sse (ws poisoned)
__global__ __launch_bounds__(1024) void vq_init(const float* __restrict__ cb,
                                                float* __restrict__ e_sq,
                                                unsigned int* __restrict__ counts,
                                                float* __restrict__ sse)
{
#pragma clang fp contract(off)
    const int k = threadIdx.x;             // single block of 1024
    const float* e = cb + k * ED;
    float r[8];
#pragma unroll
    for (int j = 0; j < 8; ++j) r[j] = e[j] * e[j];
#pragma unroll
    for (int i = 8; i < ED; i += 8)
#pragma unroll
        for (int j = 0; j < 8; ++j) r[j] = r[j] + e[i + j] * e[i + j];
    e_sq[k] = ((r[0] + r[1]) + (r[2] + r[3])) + ((r[4] + r[5]) + (r[6] + r[7]));
    counts[k] = 0u;
    if (k == 0) *sse = 0.f;
}

// ---------------------------------------------------------------------------
// main: per-token argmin over 1024 codes + fused epilogue
// __launch_bounds__(256, 1): grid gives only 2 waves/SIMD anyway (2048 waves
// on 1024 SIMDs), so don't let the occupancy heuristic cap VGPRs at 48 and
// spill zr[64] — round-2 counter evidence: VGPR=48, VALUBusy=62%, 459 us.
// ---------------------------------------------------------------------------
__global__ __launch_bounds__(256, 1) void vq_main(const float* __restrict__ z_e,
                                                  const float* __restrict__ cb,
                                                  const float* __restrict__ e_sq,
                                                  float* __restrict__ out_zq,
                                                  float* __restrict__ out_idx,
                                                  unsigned int* __restrict__ counts,
                                                  float* __restrict__ sse)
{
#pragma clang fp contract(off)
    __shared__ unsigned int hist[K_CODES];
    __shared__ float wsum[4];
    for (int i = threadIdx.x; i < K_CODES; i += 256) hist[i] = 0u;
    __syncthreads();

    const int t = blockIdx.x * 256 + threadIdx.x;   // token id

    // z into registers (64 VGPRs)
    const float4* zp = (const float4*)(z_e + (size_t)t * ED);
    float zr[ED];
#pragma unroll
    for (int i = 0; i < 16; ++i) {
        float4 v = zp[i];
        zr[4 * i + 0] = v.x; zr[4 * i + 1] = v.y;
        zr[4 * i + 2] = v.z; zr[4 * i + 3] = v.w;
    }

    // |z|^2 : numpy pairwise order, plain mul + add (no fma)
    float r[8];
#pragma unroll
    for (int j = 0; j < 8; ++j) r[j] = zr[j] * zr[j];
#pragma unroll
    for (int i = 8; i < ED; i += 8)
#pragma unroll
        for (int j = 0; j < 8; ++j) r[j] = r[j] + zr[i + j] * zr[i + j];
    const float zsq =
        ((r[0] + r[1]) + (r[2] + r[3])) + ((r[4] + r[5]) + (r[6] + r[7]));

    // argmin over codes. dot = single sequential FMA chain over d (BLAS sgemm
    // micro-kernel order). ILP from 4 independent k-chains. Codebook rows are
    // wave-uniform -> s_load/SGPR operands (v_fma_f32 v,v,s,v).
    float best = FLT_MAX;
    int bi = 0;
    for (int k = 0; k < K_CODES; k += 4) {
        const float* __restrict__ e = cb + (size_t)k * ED;   // wave-uniform
        float a0 = 0.f, a1 = 0.f, a2 = 0.f, a3 = 0.f;
#pragma unroll
        for (int d = 0; d < ED; ++d) {
            a0 = fmaf(zr[d], e[d], a0);
            a1 = fmaf(zr[d], e[d + ED], a1);
            a2 = fmaf(zr[d], e[d + 2 * ED], a2);
            a3 = fmaf(zr[d], e[d + 3 * ED], a3);
        }
        // d2 = fl(fl(zsq - 2*dot) + e_sq): fmaf(-2,dot,zsq) == fl(zsq-fl(2dot))
        float d2;
        d2 = fmaf(-2.f, a0, zsq) + e_sq[k + 0];
        if (d2 < best) { best = d2; bi = k + 0; }
        d2 = fmaf(-2.f, a1, zsq) + e_sq[k + 1];
        if (d2 < best) { best = d2; bi = k + 1; }
        d2 = fmaf(-2.f, a2, zsq) + e_sq[k + 2];
        if (d2 < best) { best = d2; bi = k + 2; }
        d2 = fmaf(-2.f, a3, zsq) + e_sq[k + 3];
        if (d2 < best) { best = d2; bi = k + 3; }
    }

    atomicAdd(&hist[bi], 1u);
    out_idx[t] = (float)bi;

    // gather selected code, write z_q, accumulate SSE
    const float4* eq = (const float4*)(cb + (size_t)bi * ED);
    float4* oz = (float4*)(out_zq + (size_t)t * ED);
    float lsse = 0.f;
#pragma unroll
    for (int i = 0; i < 16; ++i) {
        float4 q = eq[i];
        oz[i] = q;
        float dx = q.x - zr[4 * i + 0]; lsse = fmaf(dx, dx, lsse);
        float dy = q.y - zr[4 * i + 1]; lsse = fmaf(dy, dy, lsse);
        float dz = q.z - zr[4 * i + 2]; lsse = fmaf(dz, dz, lsse);
        float dw = q.w - zr[4 * i + 3]; lsse = fmaf(dw, dw, lsse);
    }

    // wave64 reduce, then 4 waves -> block, one atomic per block
#pragma unroll
    for (int off = 32; off > 0; off >>= 1)
        lsse += __shfl_down(lsse, off, 64);
    const int lane = threadIdx.x & 63;
    const int wid  = threadIdx.x >> 6;
    if (lane == 0) wsum[wid] = lsse;
    __syncthreads();
    if (threadIdx.x == 0)
        atomicAdd(sse, (wsum[0] + wsum[1]) + (wsum[2] + wsum[3]));

    // flush histogram (device-scope atomics are cross-XCD safe)
    for (int i = threadIdx.x; i < K_CODES; i += 256) {
        const unsigned int c = hist[i];
        if (c) atomicAdd(&counts[i], c);
    }
}

// ---------------------------------------------------------------------------
// final: entropy / losses scalars
// ---------------------------------------------------------------------------
__global__ __launch_bounds__(1024) void vq_final(const unsigned int* __restrict__ counts,
                                                 const float* __restrict__ sse,
                                                 float* __restrict__ out_sc)
{
    __shared__ float red[1024];
    const int i = threadIdx.x;
    const float c = (float)counts[i];
    const float p = c / (float)NTOK + 1e-10f;
    red[i] = p * logf(p);
    __syncthreads();
    for (int s = 512; s > 0; s >>= 1) {
        if (i < s) red[i] += red[i + s];
        __syncthreads();
    }
    if (i == 0) {
        const float entropy = -red[0];
        const float cbl = (*sse) / ((float)NTOK * (float)ED);
        out_sc[0] = cbl;                                   // codebook_loss
        out_sc[1] = 0.25f * cbl;                           // commitment_loss
        out_sc[2] = -0.1f * (entropy / 6.93147180559945f); // entropy_loss
        out_sc[3] = expf(entropy);                         // perplexity
    }
}

// ---------------------------------------------------------------------------
extern "C" void kernel_launch(void* const* d_in, const int* in_sizes, int n_in,
                              void* d_out, int out_size, void* d_ws, size_t ws_size,
                              hipStream_t stream)
{
    const float* z_e = (const float*)d_in[0];
    const float* cb  = (const float*)d_in[1];

    float* out   = (float*)d_out;
    float* o_zq  = out;                              // [131072,64]
    float* o_idx = out + (size_t)NTOK * ED;          // [131072] (as float)
    float* o_sc  = o_idx + NTOK;                     // 4 scalars

    float*        e_sq   = (float*)d_ws;                          // 4 KB
    unsigned int* counts = (unsigned int*)((char*)d_ws + 4096);   // 4 KB
    float*        sse    = (float*)((char*)d_ws + 8192);          // 4 B

    vq_init <<<1, 1024, 0, stream>>>(cb, e_sq, counts, sse);
    vq_main <<<NTOK / 256, 256, 0, stream>>>(z_e, cb, e_sq, o_zq, o_idx, counts, sse);
    vq_final<<<1, 1024, 0, stream>>>(counts, sse, o_sc);
}

// Round 4
// 308.180 us; speedup vs baseline: 1.7049x; 1.7049x over previous
//
#include <hip/hip_runtime.h>
#include <float.h>
#include <math.h>

#define K_CODES 1024
#define ED 64
#define NTOK 131072
#define TM 128            // tokens per block
#define TK 128            // codes per tile
#define NTILE (K_CODES / TK)

// ---------------------------------------------------------------------------
// NUMERICS ARE FROZEN (round-2 passed, absmax 3.8e-6, 0 argmin flips):
//  - zsq / e_sq: numpy pairwise_sum n=64: 8 accumulators strided 8, plain
//    mul+add (no fma), combine ((r0+r1)+(r2+r3))+((r4+r5)+(r6+r7)).
//  - dot(z,e): single sequential fmaf chain over d=0..63 (BLAS order).
//  - d2 = fmaf(-2,dot,zsq) + e_sq  (one rounding each).
//  - argmin: first index wins (strict <, ascending scan; cross-thread
//    reduce is lexicographic (value, index)).
// Do not reassociate any of these.
// ---------------------------------------------------------------------------

// init: e_sq[k] = pairwise sum cb[k][d]^2 ; zero counts + sse (ws poisoned)
__global__ __launch_bounds__(1024) void vq_init(const float* __restrict__ cb,
                                                float* __restrict__ e_sq,
                                                unsigned int* __restrict__ counts,
                                                float* __restrict__ sse)
{
#pragma clang fp contract(off)
    const int k = threadIdx.x;             // single block of 1024
    const float* e = cb + k * ED;
    float r[8];
#pragma unroll
    for (int j = 0; j < 8; ++j) r[j] = e[j] * e[j];
#pragma unroll
    for (int i = 8; i < ED; i += 8)
#pragma unroll
        for (int j = 0; j < 8; ++j) r[j] = r[j] + e[i + j] * e[i + j];
    e_sq[k] = ((r[0] + r[1]) + (r[2] + r[3])) + ((r[4] + r[5]) + (r[6] + r[7]));
    counts[k] = 0u;
    if (k == 0) *sse = 0.f;
}

// zsq[t] = numpy-pairwise |z_t|^2
__global__ __launch_bounds__(256) void vq_zsq(const float* __restrict__ z_e,
                                              float* __restrict__ zsq_g)
{
#pragma clang fp contract(off)
    const int t = blockIdx.x * 256 + threadIdx.x;
    const float4* zp = (const float4*)(z_e + (size_t)t * ED);
    float zr[ED];
#pragma unroll
    for (int i = 0; i < 16; ++i) {
        float4 v = zp[i];
        zr[4 * i + 0] = v.x; zr[4 * i + 1] = v.y;
        zr[4 * i + 2] = v.z; zr[4 * i + 3] = v.w;
    }
    float r[8];
#pragma unroll
    for (int j = 0; j < 8; ++j) r[j] = zr[j] * zr[j];
#pragma unroll
    for (int i = 8; i < ED; i += 8)
#pragma unroll
        for (int j = 0; j < 8; ++j) r[j] = r[j] + zr[i + j] * zr[i + j];
    zsq_g[t] = ((r[0] + r[1]) + (r[2] + r[3])) + ((r[4] + r[5]) + (r[6] + r[7]));
}

// ---------------------------------------------------------------------------
// main: register-blocked LDS GEMM. Block: 128 tokens x 1024 codes (8 tiles
// of 128). Thread (tx,ty): 8 tokens x 8 codes register tile; per d-step
// 4x ds_read_b128 -> 64 fmaf. 2 blocks/CU (LDS ~70KB).
// ---------------------------------------------------------------------------
__global__ __launch_bounds__(256, 2) void vq_main(const float* __restrict__ z_e,
                                                  const float* __restrict__ cb,
                                                  const float* __restrict__ e_sq,
                                                  const float* __restrict__ zsq_g,
                                                  float* __restrict__ out_zq,
                                                  float* __restrict__ out_idx,
                                                  unsigned int* __restrict__ counts,
                                                  float* __restrict__ sse)
{
#pragma clang fp contract(off)
    __shared__ float zT[ED * TM];          // zT[d*128+t]  32 KB
    __shared__ float eT[ED * TK];          // eT[d*128+c]  32 KB (reused as redbuf)
    __shared__ float zsqs[TM];
    __shared__ float esqs[TK];
    __shared__ unsigned int hist[K_CODES];
    __shared__ float wsum[4];

    const int tid = threadIdx.x;
    const int tx = tid & 15;               // code dim (16)
    const int ty = tid >> 4;               // token dim (16)
    const int B0 = blockIdx.x * TM;

    for (int i = tid; i < K_CODES; i += 256) hist[i] = 0u;

    // ---- stage zT (transpose): thread pair per token row ----
    {
        const int t = tid >> 1, dh = (tid & 1) * 32;
        const float4* src = (const float4*)(z_e + (size_t)(B0 + t) * ED + dh);
#pragma unroll
        for (int j = 0; j < 8; ++j) {
            float4 v = src[j];
            const int d = dh + 4 * j;
            zT[(d + 0) * TM + t] = v.x;
            zT[(d + 1) * TM + t] = v.y;
            zT[(d + 2) * TM + t] = v.z;
            zT[(d + 3) * TM + t] = v.w;
        }
        if (tid < TM) zsqs[tid] = zsq_g[B0 + tid];
    }

    float bestv[8];
    int   besti[8];
#pragma unroll
    for (int m = 0; m < 8; ++m) { bestv[m] = FLT_MAX; besti[m] = 0; }

    for (int tile = 0; tile < NTILE; ++tile) {
        __syncthreads();   // eT safe to overwrite; also covers zT/zsqs (tile 0)
        // ---- stage eT (transpose) ----
        {
            const int c = tid >> 1, dh = (tid & 1) * 32;
            const float4* src = (const float4*)(cb + (size_t)(tile * TK + c) * ED + dh);
#pragma unroll
            for (int j = 0; j < 8; ++j) {
                float4 v = src[j];
                const int d = dh + 4 * j;
                eT[(d + 0) * TK + c] = v.x;
                eT[(d + 1) * TK + c] = v.y;
                eT[(d + 2) * TK + c] = v.z;
                eT[(d + 3) * TK + c] = v.w;
            }
            if (tid < TK) esqs[tid] = e_sq[tile * TK + tid];
        }
        __syncthreads();

        // ---- 8x8 register-tile GEMM over d ----
        float acc[8][8];
#pragma unroll
        for (int m = 0; m < 8; ++m)
#pragma unroll
            for (int n = 0; n < 8; ++n) acc[m][n] = 0.f;

#pragma unroll 8
        for (int d = 0; d < ED; ++d) {
            const float4 za = *(const float4*)&zT[d * TM + ty * 8];
            const float4 zb = *(const float4*)&zT[d * TM + ty * 8 + 4];
            const float4 ea = *(const float4*)&eT[d * TK + tx * 4];
            const float4 eb = *(const float4*)&eT[d * TK + 64 + tx * 4];
            float zf[8] = {za.x, za.y, za.z, za.w, zb.x, zb.y, zb.z, zb.w};
            float ef[8] = {ea.x, ea.y, ea.z, ea.w, eb.x, eb.y, eb.z, eb.w};
#pragma unroll
            for (int m = 0; m < 8; ++m)
#pragma unroll
                for (int n = 0; n < 8; ++n)
                    acc[m][n] = fmaf(zf[m], ef[n], acc[m][n]);
        }

        // ---- tile epilogue: d2 + running argmin (codes ascending per thread)
#pragma unroll
        for (int m = 0; m < 8; ++m) {
            const float zq = zsqs[ty * 8 + m];
#pragma unroll
            for (int n = 0; n < 8; ++n) {
                const int cl = (n < 4) ? (tx * 4 + n) : (64 + tx * 4 + (n - 4));
                const float d2 = fmaf(-2.f, acc[m][n], zq) + esqs[cl];
                if (d2 < bestv[m]) { bestv[m] = d2; besti[m] = tile * TK + cl; }
            }
        }
    }

    // ---- cross-thread (tx) argmin reduce via redbuf (reuse eT) ----
    __syncthreads();                       // all d-loop readers of eT done
    float* red_v = eT;                     // [TM][16]
    int*   red_i = (int*)&eT[TM * 16];     // [TM][16]
#pragma unroll
    for (int m = 0; m < 8; ++m) {
        red_v[(ty * 8 + m) * 16 + tx] = bestv[m];
        red_i[(ty * 8 + m) * 16 + tx] = besti[m];
    }
    __syncthreads();

    float lsse = 0.f;
    if (tid < TM) {
        const int t = tid;
        float bv = red_v[t * 16 + 0];
        int   bi = red_i[t * 16 + 0];
#pragma unroll
        for (int x = 1; x < 16; ++x) {
            const float v = red_v[t * 16 + x];
            const int   i = red_i[t * 16 + x];
            if (v < bv || (v == bv && i < bi)) { bv = v; bi = i; }
        }
        atomicAdd(&hist[bi], 1u);
        out_idx[B0 + t] = (float)bi;

        // gather selected code, write z_q, SSE (frozen fmaf chain, d order)
        const float4* eq = (const float4*)(cb + (size_t)bi * ED);
        float4* oz = (float4*)(out_zq + (size_t)(B0 + t) * ED);
#pragma unroll
        for (int i = 0; i < 16; ++i) {
            float4 q = eq[i];
            oz[i] = q;
            const int d = 4 * i;
            float dx = q.x - zT[(d + 0) * TM + t]; lsse = fmaf(dx, dx, lsse);
            float dy = q.y - zT[(d + 1) * TM + t]; lsse = fmaf(dy, dy, lsse);
            float dz = q.z - zT[(d + 2) * TM + t]; lsse = fmaf(dz, dz, lsse);
            float dw = q.w - zT[(d + 3) * TM + t]; lsse = fmaf(dw, dw, lsse);
        }
    }

    // block SSE reduce: wave64 shfl then 4 waves -> one atomic
#pragma unroll
    for (int off = 32; off > 0; off >>= 1)
        lsse += __shfl_down(lsse, off, 64);
    const int lane = tid & 63, wid = tid >> 6;
    if (lane == 0) wsum[wid] = lsse;
    __syncthreads();
    if (tid == 0)
        atomicAdd(sse, (wsum[0] + wsum[1]) + (wsum[2] + wsum[3]));

    // flush histogram
    for (int i = tid; i < K_CODES; i += 256) {
        const unsigned int c = hist[i];
        if (c) atomicAdd(&counts[i], c);
    }
}

// ---------------------------------------------------------------------------
// final: entropy / losses scalars
// ---------------------------------------------------------------------------
__global__ __launch_bounds__(1024) void vq_final(const unsigned int* __restrict__ counts,
                                                 const float* __restrict__ sse,
                                                 float* __restrict__ out_sc)
{
    __shared__ float red[1024];
    const int i = threadIdx.x;
    const float c = (float)counts[i];
    const float p = c / (float)NTOK + 1e-10f;
    red[i] = p * logf(p);
    __syncthreads();
    for (int s = 512; s > 0; s >>= 1) {
        if (i < s) red[i] += red[i + s];
        __syncthreads();
    }
    if (i == 0) {
        const float entropy = -red[0];
        const float cbl = (*sse) / ((float)NTOK * (float)ED);
        out_sc[0] = cbl;                                   // codebook_loss
        out_sc[1] = 0.25f * cbl;                           // commitment_loss
        out_sc[2] = -0.1f * (entropy / 6.93147180559945f); // entropy_loss
        out_sc[3] = expf(entropy);                         // perplexity
    }
}

// ---------------------------------------------------------------------------
extern "C" void kernel_launch(void* const* d_in, const int* in_sizes, int n_in,
                              void* d_out, int out_size, void* d_ws, size_t ws_size,
                              hipStream_t stream)
{
    const float* z_e = (const float*)d_in[0];
    const float* cb  = (const float*)d_in[1];

    float* out   = (float*)d_out;
    float* o_zq  = out;                              // [131072,64]
    float* o_idx = out + (size_t)NTOK * ED;          // [131072] (as float)
    float* o_sc  = o_idx + NTOK;                     // 4 scalars

    float*        e_sq   = (float*)d_ws;                          // 4 KB
    unsigned int* counts = (unsigned int*)((char*)d_ws + 4096);   // 4 KB
    float*        sse    = (float*)((char*)d_ws + 8192);          // 4 B
    float*        zsq_g  = (float*)((char*)d_ws + 12288);         // 512 KB

    vq_init <<<1, 1024, 0, stream>>>(cb, e_sq, counts, sse);
    vq_zsq  <<<NTOK / 256, 256, 0, stream>>>(z_e, zsq_g);
    vq_main <<<NTOK / TM, 256, 0, stream>>>(z_e, cb, e_sq, zsq_g,
                                            o_zq, o_idx, counts, sse);
    vq_final<<<1, 1024, 0, stream>>>(counts, sse, o_sc);
}